// Round 4
// baseline (566.026 us; speedup 1.0000x reference)
//
#include <hip/hip_runtime.h>
#include <hip/hip_bf16.h>

#define BB 16
#define LL 512
#define DD 768
#define NHEAD 12
#define HALF 256      // L/2
#define KPRES 384
#define RCNT 128      // L - K  (merged src count = unpreserved count)
#define UDIM 384
#define NH2 6
#define HD 64

// ---- module-scope scratch (no d_ws dependency, no atomics) -----------------
__device__ float              g_colsum_part[BB * NHEAD * 4 * LL]; // 1.57 MB
__device__ float              g_norms[BB * LL];
__device__ unsigned long long g_nodep_part[BB * HALF * 4];        // 128 KB
__device__ int                g_unm[BB * RCNT];
__device__ int                g_srctok[BB * RCNT];
__device__ int                g_srcdst[BB * RCNT];
__device__ int                g_unp[BB * RCNT];
__device__ float              g_ctx[BB * UDIM];

// ---------------- K1: partial column sums of scores (diag excluded) ---------
// grid: BB*NHEAD*4 blocks, 512 threads; block = (b,h, 128-row chunk)
__global__ void k_colsum(const float* __restrict__ sc) {
    int blk = blockIdx.x;
    int ic = blk & 3;
    int h  = (blk >> 2) % NHEAD;
    int b  = blk / (4 * NHEAD);
    int j  = threadIdx.x;
    const float* base = sc + ((size_t)(b * NHEAD + h)) * LL * LL;
    int i0 = ic * 128;
    float acc = 0.f;
    for (int i = 0; i < 128; i++)
        acc += base[(size_t)(i0 + i) * LL + j];
    if (j >= i0 && j < i0 + 128)
        acc -= base[(size_t)j * LL + j];        // remove diagonal term
    g_colsum_part[(size_t)blk * LL + j] = acc;  // blk == (b*NHEAD+h)*4+ic
}

// ---------------- K2: per-row L2 norms --------------------------------------
// grid: BB*LL blocks, 256 threads
__global__ void k_norm(const float* __restrict__ hs) {
    int row = blockIdx.x;
    __shared__ float red[256];
    const float* src = hs + (size_t)row * DD;
    float ss = 0.f;
    for (int d = threadIdx.x; d < DD; d += 256) { float v = src[d]; ss += v * v; }
    red[threadIdx.x] = ss;
    __syncthreads();
    for (int s = 128; s > 0; s >>= 1) {
        if (threadIdx.x < s) red[threadIdx.x] += red[threadIdx.x + s];
        __syncthreads();
    }
    if (threadIdx.x == 0) g_norms[row] = sqrtf(red[0]);
}

// ---------------- K3: sim tile + fused row-argmax (no atomics) --------------
// grid: (BB,4,4); 256 threads; block = 64 even-rows x 64 odd-cols
__global__ void k_sim(const float* __restrict__ hs) {
    int b = blockIdx.x, it = blockIdx.y, jt = blockIdx.z;
    int i0 = it * 64, j0 = jt * 64;
    __shared__ float As[64][17];
    __shared__ float Bs[64][17];
    __shared__ float nA[64], nB[64];
    __shared__ unsigned long long cand[64][16];
    int t  = threadIdx.x;
    int ti = t >> 4, tj = t & 15;
    if (t < 64) nA[t] = g_norms[b * LL + 2 * (i0 + t)];
    else if (t < 128) nB[t - 64] = g_norms[b * LL + 2 * (j0 + t - 64) + 1];
    float acc[4][4];
#pragma unroll
    for (int a = 0; a < 4; a++)
#pragma unroll
        for (int c = 0; c < 4; c++) acc[a][c] = 0.f;
    const float* hb = hs + (size_t)b * LL * DD;
    __syncthreads();
    for (int d0 = 0; d0 < DD; d0 += 16) {
        for (int e = t; e < 1024; e += 256) {
            int r = e >> 4, c = e & 15;
            As[r][c] = hb[(size_t)(2 * (i0 + r)) * DD + d0 + c] / nA[r];
            Bs[r][c] = hb[(size_t)(2 * (j0 + r) + 1) * DD + d0 + c] / nB[r];
        }
        __syncthreads();
#pragma unroll
        for (int c = 0; c < 16; c++) {
            float av[4], bv[4];
#pragma unroll
            for (int a = 0; a < 4; a++) av[a] = As[ti * 4 + a][c];
#pragma unroll
            for (int a = 0; a < 4; a++) bv[a] = Bs[tj * 4 + a][c];
#pragma unroll
            for (int a = 0; a < 4; a++)
#pragma unroll
                for (int cc = 0; cc < 4; cc++) acc[a][cc] += av[a] * bv[cc];
        }
        __syncthreads();
    }
    // pack (sim, smaller-j-wins) into sortable u64; per-thread best over 4 cols
#pragma unroll
    for (int a = 0; a < 4; a++) {
        unsigned long long bp = 0ULL;
#pragma unroll
        for (int c = 0; c < 4; c++) {
            int jg = j0 + tj * 4 + c;
            unsigned u = __float_as_uint(acc[a][c]);
            u = (u & 0x80000000u) ? ~u : (u | 0x80000000u);
            unsigned long long p = ((unsigned long long)u << 32) | (unsigned long long)(255 - jg);
            if (p > bp) bp = p;
        }
        cand[ti * 4 + a][tj] = bp;
    }
    __syncthreads();
    if (t < 64) {
        unsigned long long m = cand[t][0];
#pragma unroll
        for (int c2 = 1; c2 < 16; c2++) { unsigned long long v = cand[t][c2]; if (v > m) m = v; }
        g_nodep_part[((size_t)b * HALF + i0 + t) * 4 + jt] = m;
    }
}

// ---------------- K4: top-K mask + unpreserved list (ascending) -------------
// grid: BB blocks, 512 threads
__global__ void k_select(int* dummy) {
    int b = blockIdx.x, j = threadIdx.x;
    __shared__ float v[LL];
    __shared__ int pos[LL];
    float imp = 0.f;
    for (int p = 0; p < NHEAD * 4; p++)
        imp += g_colsum_part[((size_t)b * NHEAD * 4 + p) * LL + j];
    v[j] = imp;
    __syncthreads();
    int cnt = 0;
    for (int k = 0; k < LL; k++) {
        float vk = v[k];
        cnt += (vk > imp) || (vk == imp && k < j);
    }
    int notp = (cnt >= KPRES) ? 1 : 0;    // rank >= K -> unpreserved
    pos[j] = notp;
    __syncthreads();
    for (int s = 1; s < LL; s <<= 1) {
        int add = (j >= s) ? pos[j - s] : 0;
        __syncthreads();
        pos[j] += add;
        __syncthreads();
    }
    if (notp) g_unp[b * RCNT + pos[j] - 1] = j;
}

// ---------------- K5: edge ranking (descending stable) ----------------------
// grid: BB blocks, 256 threads
__global__ void k_edges(int* dummy) {
    int b = blockIdx.x, i = threadIdx.x;
    __shared__ float nm[HALF];
    __shared__ int   ni[HALF];
    unsigned long long p = g_nodep_part[((size_t)b * HALF + i) * 4 + 0];
#pragma unroll
    for (int q = 1; q < 4; q++) {
        unsigned long long w = g_nodep_part[((size_t)b * HALF + i) * 4 + q];
        if (w > p) p = w;
    }
    unsigned u = (unsigned)(p >> 32);
    unsigned bits = (u & 0x80000000u) ? (u & 0x7FFFFFFFu) : ~u;
    float v = __uint_as_float(bits);
    int j = 255 - (int)(p & 0xFFFFFFFFu);
    nm[i] = v; ni[i] = j;
    __syncthreads();
    int cnt = 0;
    for (int k = 0; k < HALF; k++) {
        float vk = nm[k];
        cnt += (vk > v) || (vk == v && k < i);
    }
    if (cnt < RCNT) {              // merged (src) edges, rank order
        g_srctok[b * RCNT + cnt] = i;
        g_srcdst[b * RCNT + cnt] = ni[i];
    } else {                       // unmerged even tokens, rank order
        g_unm[b * RCNT + (cnt - RCNT)] = 2 * i;
    }
}

// ---------------- K6: assemble output rows 0..384 (merge fused) -------------
// grid: BB*385 blocks, 256 threads
__global__ void k_rows(const float* __restrict__ hs, float* __restrict__ out) {
    int blk = blockIdx.x;
    int row = blk % 385, b = blk / 385;
    int t = threadIdx.x;
    float* o = out + ((size_t)b * 386 + row) * DD;
    if (row == 0) {
        const float* s = hs + (size_t)b * LL * DD;
        for (int d = t; d < DD; d += 256) o[d] = s[d];
    } else if (row <= RCNT) {
        int tok = g_unm[b * RCNT + row - 1];
        const float* s = hs + ((size_t)b * LL + tok) * DD;
        for (int d = t; d < DD; d += 256) o[d] = s[d];
    } else {
        int j = row - 1 - RCNT;
        __shared__ int ss[RCNT], sd[RCNT];
        if (t < RCNT) { ss[t] = g_srctok[b * RCNT + t]; sd[t] = g_srcdst[b * RCNT + t]; }
        __syncthreads();
        const float* dstrow = hs + ((size_t)b * LL + 2 * j + 1) * DD;
        float acc[3];
#pragma unroll
        for (int c = 0; c < 3; c++) acc[c] = dstrow[t + 256 * c];
        float cnt = 1.f;
        for (int s2 = 0; s2 < RCNT; s2++) {      // ascending rank == np.add.at order
            if (sd[s2] == j) {
                const float* sr = hs + ((size_t)b * LL + 2 * ss[s2]) * DD;
#pragma unroll
                for (int c = 0; c < 3; c++) acc[c] += sr[t + 256 * c];
                cnt += 1.f;
            }
        }
#pragma unroll
        for (int c = 0; c < 3; c++) o[t + 256 * c] = acc[c] / cnt;
    }
}

// ---------------- K7: fused q/k/v projection + attention --------------------
// grid: BB*NH2 blocks, 256 threads; one (batch, head) each
__global__ void k_attn(const float* __restrict__ hs,
                       const float* __restrict__ Wq, const float* __restrict__ bq,
                       const float* __restrict__ Wk, const float* __restrict__ bk,
                       const float* __restrict__ Wv, const float* __restrict__ bv) {
    int h = blockIdx.x % NH2, b = blockIdx.x / NH2;
    int t = threadIdx.x;
    __shared__ float h0[DD];
    __shared__ float wk2[DD];
    __shared__ float hbar[DD];
    __shared__ float qs[HD];
    __shared__ float red[256];
    __shared__ float att[RCNT];
    __shared__ int   toks[RCNT];
    __shared__ float qbk;
    const float* hb = hs + (size_t)b * LL * DD;
    for (int d = t; d < DD; d += 256) h0[d] = hb[d];
    if (t < RCNT) toks[t] = g_unp[b * RCNT + t];
    __syncthreads();
    // --- q head projection: 4 partial sums of 192 per output dim ---
    {
        int u = t & 63, part = t >> 6;
        float a = 0.f;
        for (int d = part * 192; d < part * 192 + 192; d++)
            a += h0[d] * Wq[(size_t)d * UDIM + h * HD + u];
        red[t] = a;
        __syncthreads();
        if (t < HD)
            qs[t] = bq[h * HD + t] + red[t] + red[t + 64] + red[t + 128] + red[t + 192];
        __syncthreads();
    }
    // --- wk2 = Wk_head @ q  (so logits = H . wk2 + q.bk) ---
    for (int d = t; d < DD; d += 256) {
        float a = 0.f;
        const float* wrow = Wk + (size_t)d * UDIM + h * HD;
#pragma unroll 8
        for (int u = 0; u < HD; u++) a += qs[u] * wrow[u];
        wk2[d] = a;
    }
    if (t == 0) {
        float a = 0.f;
        for (int u = 0; u < HD; u++) a += qs[u] * bk[h * HD + u];
        qbk = a;
    }
    __syncthreads();
    // --- logits + softmax over the 128 unpreserved tokens ---
    float lg = -1e30f;
    if (t < RCNT) {
        const float* hr = hb + (size_t)toks[t] * DD;
        float a = qbk;
        for (int d = 0; d < DD; d++) a += wk2[d] * hr[d];
        lg = a * 0.125f;                              // 1/sqrt(64)
    }
    red[t] = lg;
    __syncthreads();
    for (int s = 128; s > 0; s >>= 1) {
        if (t < s) red[t] = fmaxf(red[t], red[t + s]);
        __syncthreads();
    }
    float mx = red[0];
    __syncthreads();
    float e = (t < RCNT) ? expf(lg - mx) : 0.f;
    red[t] = e;
    __syncthreads();
    for (int s = 128; s > 0; s >>= 1) {
        if (t < s) red[t] += red[t + s];
        __syncthreads();
    }
    float inv = 1.f / red[0];
    __syncthreads();
    if (t < RCNT) att[t] = e * inv;
    __syncthreads();
    // --- hbar = sum_t att_t * H_t ---
    for (int d = t; d < DD; d += 256) {
        float a = 0.f;
        for (int s2 = 0; s2 < RCNT; s2++)
            a += att[s2] * hb[(size_t)toks[s2] * DD + d];
        hbar[d] = a;
    }
    __syncthreads();
    // --- ctx = hbar @ Wv_head + bv  (bv exact since sum(att)=1) ---
    {
        int u = t & 63, part = t >> 6;
        float a = 0.f;
        for (int d = part * 192; d < part * 192 + 192; d++)
            a += hbar[d] * Wv[(size_t)d * UDIM + h * HD + u];
        red[t] = a;
        __syncthreads();
        if (t < HD)
            g_ctx[b * UDIM + h * HD + t] =
                bv[h * HD + t] + red[t] + red[t + 64] + red[t + 128] + red[t + 192];
    }
}

// ---------------- K8: new_token = ctx @ Wo + bo (output row 385) ------------
// grid: BB blocks, 768 threads
__global__ void k_newtok(const float* __restrict__ Wo, const float* __restrict__ bo,
                         float* __restrict__ out) {
    int b = blockIdx.x, dd = threadIdx.x;
    __shared__ float c[UDIM];
    if (dd < UDIM) c[dd] = g_ctx[b * UDIM + dd];
    __syncthreads();
    float acc = bo[dd];
    for (int u = 0; u < UDIM; u++)
        acc += c[u] * Wo[(size_t)u * DD + dd];
    out[((size_t)b * 386 + 385) * DD + dd] = acc;
}

extern "C" void kernel_launch(void* const* d_in, const int* in_sizes, int n_in,
                              void* d_out, int out_size, void* d_ws, size_t ws_size,
                              hipStream_t stream) {
    const float* hs = (const float*)d_in[0];
    const float* sc = (const float*)d_in[1];
    const float* Wq = (const float*)d_in[2];
    const float* bq = (const float*)d_in[3];
    const float* Wk = (const float*)d_in[4];
    const float* bk = (const float*)d_in[5];
    const float* Wv = (const float*)d_in[6];
    const float* bv = (const float*)d_in[7];
    const float* Wo = (const float*)d_in[8];
    const float* bo = (const float*)d_in[9];
    float* out = (float*)d_out;
    (void)d_ws; (void)ws_size;

    k_colsum<<<BB * NHEAD * 4, 512, 0, stream>>>(sc);
    k_norm<<<BB * LL, 256, 0, stream>>>(hs);
    k_sim<<<dim3(BB, 4, 4), 256, 0, stream>>>(hs);
    k_select<<<BB, 512, 0, stream>>>(nullptr);
    k_edges<<<BB, 256, 0, stream>>>(nullptr);
    k_rows<<<BB * 385, 256, 0, stream>>>(hs, out);
    k_attn<<<BB * NH2, 256, 0, stream>>>(hs, Wq, bq, Wk, bk, Wv, bv);
    k_newtok<<<BB, DD, 0, stream>>>(Wo, bo, out);
}

// Round 5
// 541.804 us; speedup vs baseline: 1.0447x; 1.0447x over previous
//
#include <hip/hip_runtime.h>
#include <hip/hip_bf16.h>

#define BB 16
#define LL 512
#define DD 768
#define NHEAD 12
#define HALF 256      // L/2
#define KPRES 384
#define RCNT 128      // L - K  (merged src count = unpreserved count)
#define UDIM 384
#define NH2 6
#define HD 64

// ---- small module-scope scratch (deterministic, no atomics) ----------------
__device__ float              g_colsum_part[BB * NHEAD * 4 * LL]; // 1.57 MB
__device__ unsigned long long g_nodep_part[BB * HALF * 4];        // 128 KB
__device__ int                g_unm[BB * RCNT];
__device__ int                g_srctok[BB * RCNT];
__device__ int                g_srcdst[BB * RCNT];
__device__ int                g_unp[BB * RCNT];
__device__ float              g_ctx[BB * UDIM];

// ---------------- K1: partial column sums of scores (diag excluded) ---------
// grid: BB*NHEAD*4 blocks, 128 threads; block = (b,h, 128-row chunk); float4 cols
__global__ void k_colsum(const float* __restrict__ sc) {
    int blk = blockIdx.x;
    int ic = blk & 3;
    int bh = blk >> 2;                 // b*NHEAD + h
    int j4 = threadIdx.x;              // 128 threads, 4 columns each
    const float* base = sc + (size_t)bh * LL * LL;
    int i0 = ic * 128;
    float ax = 0.f, ay = 0.f, az = 0.f, aw = 0.f;
    for (int i = 0; i < 128; i++) {    // ascending i: same fp order as round 4
        float4 v = ((const float4*)(base + (size_t)(i0 + i) * LL))[j4];
        ax += v.x; ay += v.y; az += v.z; aw += v.w;
    }
#pragma unroll
    for (int c = 0; c < 4; c++) {
        int cj = 4 * j4 + c;
        if (cj >= i0 && cj < i0 + 128) {
            float d = base[(size_t)cj * LL + cj];
            if (c == 0) ax -= d; else if (c == 1) ay -= d;
            else if (c == 2) az -= d; else aw -= d;
        }
    }
    float* o = &g_colsum_part[(size_t)blk * LL + 4 * j4];
    o[0] = ax; o[1] = ay; o[2] = az; o[3] = aw;
}

// ---------------- K2: normalized metric rows -> d_ws ------------------------
// grid: BB*LL blocks, 256 threads; same norm reduction bits as before
__global__ void k_metric(const float* __restrict__ hs, float* __restrict__ metric) {
    int row = blockIdx.x;
    int t = threadIdx.x;
    __shared__ float red[256];
    const float* src = hs + (size_t)row * DD;
    float v0 = src[t], v1 = src[t + 256], v2 = src[t + 512];
    red[t] = ((0.f + v0 * v0) + v1 * v1) + v2 * v2;   // same assoc as loop
    __syncthreads();
    for (int s = 128; s > 0; s >>= 1) {
        if (t < s) red[t] += red[t + s];
        __syncthreads();
    }
    float nrm = sqrtf(red[0]);
    float* dst = metric + (size_t)row * DD;
    dst[t] = v0 / nrm; dst[t + 256] = v1 / nrm; dst[t + 512] = v2 / nrm;
}

// ---------------- K3: sim tile + fused row-argmax ---------------------------
// grid: (BB,4,4); 256 threads; block = 64 even-rows x 64 odd-cols
__global__ void k_sim(const float* __restrict__ metric) {
    int b = blockIdx.x, it = blockIdx.y, jt = blockIdx.z;
    int i0 = it * 64, j0 = jt * 64;
    __shared__ float As[64][20];       // pad 20: rows 80B apart, 16B-aligned
    __shared__ float Bs[64][20];
    __shared__ unsigned long long cand[64][16];
    int t  = threadIdx.x;
    int ti = t >> 4, tj = t & 15;
    float acc[4][4];
#pragma unroll
    for (int a = 0; a < 4; a++)
#pragma unroll
        for (int c = 0; c < 4; c++) acc[a][c] = 0.f;
    const float* mb = metric + (size_t)b * LL * DD;
    int sr = t >> 2, sc4 = t & 3;      // staging: thread -> (row, float4-slot)
    for (int d0 = 0; d0 < DD; d0 += 16) {
        float4 a4 = ((const float4*)(mb + (size_t)(2 * (i0 + sr)) * DD + d0))[sc4];
        float4 b4 = ((const float4*)(mb + (size_t)(2 * (j0 + sr) + 1) * DD + d0))[sc4];
        __syncthreads();
        *(float4*)&As[sr][4 * sc4] = a4;
        *(float4*)&Bs[sr][4 * sc4] = b4;
        __syncthreads();
#pragma unroll
        for (int c4 = 0; c4 < 4; c4++) {
            float av[4][4], bv[4][4];  // [row/col][k-comp]
#pragma unroll
            for (int a = 0; a < 4; a++) {
                float4 v = *(const float4*)&As[ti * 4 + a][4 * c4];
                av[a][0] = v.x; av[a][1] = v.y; av[a][2] = v.z; av[a][3] = v.w;
            }
#pragma unroll
            for (int a = 0; a < 4; a++) {
                float4 v = *(const float4*)&Bs[tj * 4 + a][4 * c4];
                bv[a][0] = v.x; bv[a][1] = v.y; bv[a][2] = v.z; bv[a][3] = v.w;
            }
#pragma unroll
            for (int k = 0; k < 4; k++)    // k ascending: same fp order
#pragma unroll
                for (int a = 0; a < 4; a++)
#pragma unroll
                    for (int cc = 0; cc < 4; cc++)
                        acc[a][cc] += av[a][k] * bv[cc][k];
        }
    }
    // pack (sim, smaller-j-wins) into sortable u64; per-thread best over 4 cols
#pragma unroll
    for (int a = 0; a < 4; a++) {
        unsigned long long bp = 0ULL;
#pragma unroll
        for (int c = 0; c < 4; c++) {
            int jg = j0 + tj * 4 + c;
            unsigned u = __float_as_uint(acc[a][c]);
            u = (u & 0x80000000u) ? ~u : (u | 0x80000000u);
            unsigned long long p = ((unsigned long long)u << 32) | (unsigned long long)(255 - jg);
            if (p > bp) bp = p;
        }
        cand[ti * 4 + a][tj] = bp;
    }
    __syncthreads();
    if (t < 64) {
        unsigned long long m = cand[t][0];
#pragma unroll
        for (int c2 = 1; c2 < 16; c2++) { unsigned long long v = cand[t][c2]; if (v > m) m = v; }
        g_nodep_part[((size_t)b * HALF + i0 + t) * 4 + jt] = m;
    }
}

// ---------------- K4: top-K mask + unpreserved list (ascending) -------------
// grid: BB blocks, 512 threads
__global__ void k_select(int* dummy) {
    int b = blockIdx.x, j = threadIdx.x;
    __shared__ float v[LL];
    __shared__ int pos[LL];
    float imp = 0.f;
    for (int p = 0; p < NHEAD * 4; p++)
        imp += g_colsum_part[((size_t)b * NHEAD * 4 + p) * LL + j];
    v[j] = imp;
    __syncthreads();
    int cnt = 0;
    for (int k = 0; k < LL; k++) {
        float vk = v[k];
        cnt += (vk > imp) || (vk == imp && k < j);
    }
    int notp = (cnt >= KPRES) ? 1 : 0;    // rank >= K -> unpreserved
    pos[j] = notp;
    __syncthreads();
    for (int s = 1; s < LL; s <<= 1) {
        int add = (j >= s) ? pos[j - s] : 0;
        __syncthreads();
        pos[j] += add;
        __syncthreads();
    }
    if (notp) g_unp[b * RCNT + pos[j] - 1] = j;
}

// ---------------- K5: edge ranking (descending stable) ----------------------
// grid: BB blocks, 256 threads
__global__ void k_edges(int* dummy) {
    int b = blockIdx.x, i = threadIdx.x;
    __shared__ float nm[HALF];
    __shared__ int   ni[HALF];
    unsigned long long p = g_nodep_part[((size_t)b * HALF + i) * 4 + 0];
#pragma unroll
    for (int q = 1; q < 4; q++) {
        unsigned long long w = g_nodep_part[((size_t)b * HALF + i) * 4 + q];
        if (w > p) p = w;
    }
    unsigned u = (unsigned)(p >> 32);
    unsigned bits = (u & 0x80000000u) ? (u & 0x7FFFFFFFu) : ~u;
    float v = __uint_as_float(bits);
    int j = 255 - (int)(p & 0xFFFFFFFFu);
    nm[i] = v; ni[i] = j;
    __syncthreads();
    int cnt = 0;
    for (int k = 0; k < HALF; k++) {
        float vk = nm[k];
        cnt += (vk > v) || (vk == v && k < i);
    }
    if (cnt < RCNT) {              // merged (src) edges, rank order
        g_srctok[b * RCNT + cnt] = i;
        g_srcdst[b * RCNT + cnt] = ni[i];
    } else {                       // unmerged even tokens, rank order
        g_unm[b * RCNT + (cnt - RCNT)] = 2 * i;
    }
}

// ---------------- K6: assemble output rows 0..384 (merge fused) -------------
// grid: BB*385 blocks, 192 threads (one float4 per thread)
__global__ void k_rows(const float* __restrict__ hs, float* __restrict__ out) {
    int blk = blockIdx.x;
    int row = blk % 385, b = blk / 385;
    int t = threadIdx.x;
    float4* o4 = (float4*)(out + ((size_t)b * 386 + row) * DD);
    if (row == 0) {
        const float4* s4 = (const float4*)(hs + (size_t)b * LL * DD);
        o4[t] = s4[t];
    } else if (row <= RCNT) {
        int tok = g_unm[b * RCNT + row - 1];
        const float4* s4 = (const float4*)(hs + ((size_t)b * LL + tok) * DD);
        o4[t] = s4[t];
    } else {
        int j = row - 1 - RCNT;
        __shared__ int ss[RCNT], sd[RCNT];
        if (t < RCNT) { ss[t] = g_srctok[b * RCNT + t]; sd[t] = g_srcdst[b * RCNT + t]; }
        __syncthreads();
        float4 acc = ((const float4*)(hs + ((size_t)b * LL + 2 * j + 1) * DD))[t];
        float cnt = 1.f;
        for (int s2 = 0; s2 < RCNT; s2++) {      // ascending rank == np.add.at order
            if (sd[s2] == j) {
                float4 v = ((const float4*)(hs + ((size_t)b * LL + 2 * ss[s2]) * DD))[t];
                acc.x += v.x; acc.y += v.y; acc.z += v.z; acc.w += v.w;
                cnt += 1.f;
            }
        }
        float inv_applied; (void)inv_applied;
        float4 r; r.x = acc.x / cnt; r.y = acc.y / cnt; r.z = acc.z / cnt; r.w = acc.w / cnt;
        o4[t] = r;
    }
}

// ---------------- K7: fused q/k/v projection + attention --------------------
// grid: BB*NH2 blocks, 256 threads; one (batch, head) each
__global__ void k_attn(const float* __restrict__ hs,
                       const float* __restrict__ Wq, const float* __restrict__ bq,
                       const float* __restrict__ Wk, const float* __restrict__ bk,
                       const float* __restrict__ Wv, const float* __restrict__ bv) {
    int h = blockIdx.x % NH2, b = blockIdx.x / NH2;
    int t = threadIdx.x;
    __shared__ float h0[DD];
    __shared__ float wk2[DD];
    __shared__ float hbar[DD];
    __shared__ float qs[HD];
    __shared__ float red[256];
    __shared__ float att[RCNT];
    __shared__ int   toks[RCNT];
    __shared__ float qbk;
    const float* hb = hs + (size_t)b * LL * DD;
    for (int d = t; d < DD; d += 256) h0[d] = hb[d];
    if (t < RCNT) toks[t] = g_unp[b * RCNT + t];
    __syncthreads();
    // --- q head projection: 4 partial sums of 192 per output dim ---
    {
        int u = t & 63, part = t >> 6;
        float a = 0.f;
        for (int d = part * 192; d < part * 192 + 192; d++)
            a += h0[d] * Wq[(size_t)d * UDIM + h * HD + u];
        red[t] = a;
        __syncthreads();
        if (t < HD)
            qs[t] = bq[h * HD + t] + red[t] + red[t + 64] + red[t + 128] + red[t + 192];
        __syncthreads();
    }
    // --- wk2 = Wk_head @ q  (so logits = H . wk2 + q.bk) ---
    for (int d = t; d < DD; d += 256) {
        const float4* wrow = (const float4*)(Wk + (size_t)d * UDIM + h * HD);
        const float4* q4 = (const float4*)qs;
        float4 s4 = {0.f, 0.f, 0.f, 0.f};
#pragma unroll
        for (int u4 = 0; u4 < 16; u4++) {
            float4 w = wrow[u4], q = q4[u4];
            s4.x += q.x * w.x; s4.y += q.y * w.y; s4.z += q.z * w.z; s4.w += q.w * w.w;
        }
        wk2[d] = (s4.x + s4.y) + (s4.z + s4.w);
    }
    if (t == 0) {
        float a = 0.f;
        for (int u = 0; u < HD; u++) a += qs[u] * bk[h * HD + u];
        qbk = a;
    }
    __syncthreads();
    // --- logits + softmax over the 128 unpreserved tokens ---
    float lg = -1e30f;
    if (t < RCNT) {
        const float4* hr4 = (const float4*)(hb + (size_t)toks[t] * DD);
        const float4* wk4 = (const float4*)wk2;
        float4 s4 = {0.f, 0.f, 0.f, 0.f};
        for (int d4 = 0; d4 < DD / 4; d4++) {
            float4 w = wk4[d4], x = hr4[d4];
            s4.x += w.x * x.x; s4.y += w.y * x.y; s4.z += w.z * x.z; s4.w += w.w * x.w;
        }
        lg = (qbk + (s4.x + s4.y) + (s4.z + s4.w)) * 0.125f;   // 1/sqrt(64)
    }
    red[t] = lg;
    __syncthreads();
    for (int s = 128; s > 0; s >>= 1) {
        if (t < s) red[t] = fmaxf(red[t], red[t + s]);
        __syncthreads();
    }
    float mx = red[0];
    __syncthreads();
    float e = (t < RCNT) ? expf(lg - mx) : 0.f;
    red[t] = e;
    __syncthreads();
    for (int s = 128; s > 0; s >>= 1) {
        if (t < s) red[t] += red[t + s];
        __syncthreads();
    }
    float inv = 1.f / red[0];
    __syncthreads();
    if (t < RCNT) att[t] = e * inv;
    __syncthreads();
    // --- hbar = sum_t att_t * H_t (float4 over d, coalesced) ---
    if (t < DD / 4) {
        float4 a4 = {0.f, 0.f, 0.f, 0.f};
        for (int s2 = 0; s2 < RCNT; s2++) {
            float w = att[s2];
            float4 x = ((const float4*)(hb + (size_t)toks[s2] * DD))[t];
            a4.x += w * x.x; a4.y += w * x.y; a4.z += w * x.z; a4.w += w * x.w;
        }
        *(float4*)&hbar[4 * t] = a4;
    }
    __syncthreads();
    // --- ctx = hbar @ Wv_head + bv ---
    {
        int u = t & 63, part = t >> 6;
        float a = 0.f;
        for (int d = part * 192; d < part * 192 + 192; d++)
            a += hbar[d] * Wv[(size_t)d * UDIM + h * HD + u];
        red[t] = a;
        __syncthreads();
        if (t < HD)
            g_ctx[b * UDIM + h * HD + t] =
                bv[h * HD + t] + red[t] + red[t + 64] + red[t + 128] + red[t + 192];
    }
}

// ---------------- K8: new_token = ctx @ Wo + bo (output row 385) ------------
// grid: BB blocks, 768 threads
__global__ void k_newtok(const float* __restrict__ Wo, const float* __restrict__ bo,
                         float* __restrict__ out) {
    int b = blockIdx.x, dd = threadIdx.x;
    __shared__ float c[UDIM];
    if (dd < UDIM) c[dd] = g_ctx[b * UDIM + dd];
    __syncthreads();
    float acc = bo[dd];
    for (int u = 0; u < UDIM; u++)
        acc += c[u] * Wo[(size_t)u * DD + dd];
    out[((size_t)b * 386 + 385) * DD + dd] = acc;
}

extern "C" void kernel_launch(void* const* d_in, const int* in_sizes, int n_in,
                              void* d_out, int out_size, void* d_ws, size_t ws_size,
                              hipStream_t stream) {
    const float* hs = (const float*)d_in[0];
    const float* sc = (const float*)d_in[1];
    const float* Wq = (const float*)d_in[2];
    const float* bq = (const float*)d_in[3];
    const float* Wk = (const float*)d_in[4];
    const float* bk = (const float*)d_in[5];
    const float* Wv = (const float*)d_in[6];
    const float* bv = (const float*)d_in[7];
    const float* Wo = (const float*)d_in[8];
    const float* bo = (const float*)d_in[9];
    float* out = (float*)d_out;
    float* metric = (float*)d_ws;    // 16*512*768*4 = 25.2 MB (ws ~805 MB)

    k_colsum<<<BB * NHEAD * 4, 128, 0, stream>>>(sc);
    k_metric<<<BB * LL, 256, 0, stream>>>(hs, metric);
    k_sim<<<dim3(BB, 4, 4), 256, 0, stream>>>(metric);
    k_select<<<BB, 512, 0, stream>>>(nullptr);
    k_edges<<<BB, 256, 0, stream>>>(nullptr);
    k_rows<<<BB * 385, 192, 0, stream>>>(hs, out);
    k_attn<<<BB * NH2, 256, 0, stream>>>(hs, Wq, bq, Wk, bk, Wv, bv);
    k_newtok<<<BB, DD, 0, stream>>>(Wo, bo, out);
}

// Round 6
// 527.934 us; speedup vs baseline: 1.0722x; 1.0263x over previous
//
#include <hip/hip_runtime.h>
#include <hip/hip_bf16.h>

#define BB 16
#define LL 512
#define DD 768
#define NHEAD 12
#define HALF 256      // L/2
#define KPRES 384
#define RCNT 128      // L - K  (merged src count = unpreserved count)
#define UDIM 384
#define NH2 6
#define HD 64

// ---- small module-scope scratch (deterministic, no atomics) ----------------
__device__ float              g_colsum_part[BB * NHEAD * 4 * LL]; // 1.57 MB
__device__ unsigned long long g_nodep_part[BB * HALF * 4];        // 128 KB
__device__ int                g_unm[BB * RCNT];
__device__ int                g_srctok[BB * RCNT];
__device__ int                g_srcdst[BB * RCNT];
__device__ int                g_unp[BB * RCNT];
__device__ float              g_ctx[BB * UDIM];

// ---------------- K1: partial column sums of scores (diag excluded) ---------
// grid: BB*NHEAD*4 blocks, 128 threads; block = (b,h, 128-row chunk); float4 cols
__global__ void k_colsum(const float* __restrict__ sc) {
    int blk = blockIdx.x;
    int ic = blk & 3;
    int bh = blk >> 2;                 // b*NHEAD + h
    int j4 = threadIdx.x;              // 128 threads, 4 columns each
    const float* base = sc + (size_t)bh * LL * LL;
    int i0 = ic * 128;
    float ax = 0.f, ay = 0.f, az = 0.f, aw = 0.f;
    for (int i = 0; i < 128; i++) {    // ascending i: fixed fp order
        float4 v = ((const float4*)(base + (size_t)(i0 + i) * LL))[j4];
        ax += v.x; ay += v.y; az += v.z; aw += v.w;
    }
#pragma unroll
    for (int c = 0; c < 4; c++) {
        int cj = 4 * j4 + c;
        if (cj >= i0 && cj < i0 + 128) {
            float d = base[(size_t)cj * LL + cj];
            if (c == 0) ax -= d; else if (c == 1) ay -= d;
            else if (c == 2) az -= d; else aw -= d;
        }
    }
    float* o = &g_colsum_part[(size_t)blk * LL + 4 * j4];
    o[0] = ax; o[1] = ay; o[2] = az; o[3] = aw;
}

// ---------------- K2: normalized metric rows -> d_ws ------------------------
// grid: BB*LL blocks, 256 threads
__global__ void k_metric(const float* __restrict__ hs, float* __restrict__ metric) {
    int row = blockIdx.x;
    int t = threadIdx.x;
    __shared__ float red[256];
    const float* src = hs + (size_t)row * DD;
    float v0 = src[t], v1 = src[t + 256], v2 = src[t + 512];
    red[t] = ((0.f + v0 * v0) + v1 * v1) + v2 * v2;
    __syncthreads();
    for (int s = 128; s > 0; s >>= 1) {
        if (t < s) red[t] += red[t + s];
        __syncthreads();
    }
    float nrm = sqrtf(red[0]);
    float* dst = metric + (size_t)row * DD;
    dst[t] = v0 / nrm; dst[t + 256] = v1 / nrm; dst[t + 512] = v2 / nrm;
}

// ---------------- K3: sim tile + fused row-argmax ---------------------------
// grid: (BB,4,4); 256 threads; block = 64 even-rows x 64 odd-cols
// B stored TRANSPOSED in LDS (conflict-free frag reads); global prefetch.
__global__ void k_sim(const float* __restrict__ metric) {
    int b = blockIdx.x, it = blockIdx.y, jt = blockIdx.z;
    int i0 = it * 64, j0 = jt * 64;
    __shared__ float As[64][20];       // rows 80 B apart: 2-way on frag reads (free)
    __shared__ float BsT[16][68];      // [k][col], pad 68: frag reads conflict-free
    __shared__ unsigned long long cand[64][16];
    int t  = threadIdx.x;
    int ti = t >> 4, tj = t & 15;
    float acc[4][4];
#pragma unroll
    for (int a = 0; a < 4; a++)
#pragma unroll
        for (int c = 0; c < 4; c++) acc[a][c] = 0.f;
    const float* mb = metric + (size_t)b * LL * DD;
    int sr = t >> 2, sc4 = t & 3;      // staging: thread -> (row, float4-slot)
    const float* arow = mb + (size_t)(2 * (i0 + sr)) * DD;
    const float* brow = mb + (size_t)(2 * (j0 + sr) + 1) * DD;
    float4 a4 = ((const float4*)arow)[sc4];          // prefetch step 0
    float4 b4 = ((const float4*)brow)[sc4];
    for (int s = 0; s < 48; s++) {
        __syncthreads();
        *(float4*)&As[sr][4 * sc4] = a4;
        BsT[4 * sc4 + 0][sr] = b4.x;
        BsT[4 * sc4 + 1][sr] = b4.y;
        BsT[4 * sc4 + 2][sr] = b4.z;
        BsT[4 * sc4 + 3][sr] = b4.w;
        __syncthreads();
        if (s + 1 < 48) {                            // prefetch next tile
            int d0 = (s + 1) * 16;
            a4 = ((const float4*)(arow + d0))[sc4];
            b4 = ((const float4*)(brow + d0))[sc4];
        }
#pragma unroll
        for (int c4 = 0; c4 < 4; c4++) {
            float4 av[4], bk4[4];
#pragma unroll
            for (int a = 0; a < 4; a++) av[a] = *(const float4*)&As[ti * 4 + a][4 * c4];
#pragma unroll
            for (int k = 0; k < 4; k++) bk4[k] = *(const float4*)&BsT[4 * c4 + k][4 * tj];
#pragma unroll
            for (int k = 0; k < 4; k++) {            // k ascending: same fp order
#pragma unroll
                for (int a = 0; a < 4; a++) {
                    float ak = ((const float*)&av[a])[k];
#pragma unroll
                    for (int c = 0; c < 4; c++)
                        acc[a][c] += ak * ((const float*)&bk4[k])[c];
                }
            }
        }
    }
    // pack (sim, smaller-j-wins) into sortable u64; per-thread best over 4 cols
#pragma unroll
    for (int a = 0; a < 4; a++) {
        unsigned long long bp = 0ULL;
#pragma unroll
        for (int c = 0; c < 4; c++) {
            int jg = j0 + tj * 4 + c;
            unsigned u = __float_as_uint(acc[a][c]);
            u = (u & 0x80000000u) ? ~u : (u | 0x80000000u);
            unsigned long long p = ((unsigned long long)u << 32) | (unsigned long long)(255 - jg);
            if (p > bp) bp = p;
        }
        cand[ti * 4 + a][tj] = bp;
    }
    __syncthreads();
    if (t < 64) {
        unsigned long long m = cand[t][0];
#pragma unroll
        for (int c2 = 1; c2 < 16; c2++) { unsigned long long v = cand[t][c2]; if (v > m) m = v; }
        g_nodep_part[((size_t)b * HALF + i0 + t) * 4 + jt] = m;
    }
}

// ---------------- K4: top-K select (512 thr) + edge ranking (256 thr) -------
// grid: BB blocks, 512 threads
__global__ void k_seledge(int* dummy) {
    int b = blockIdx.x, t = threadIdx.x;
    __shared__ float v[LL];
    __shared__ int pos[LL];
    __shared__ float nm[HALF];
    __shared__ int   ni[HALF];
    // --- phase 1: importance rank + compaction (thread t = token j) ---
    float imp = 0.f;
    for (int p = 0; p < NHEAD * 4; p++)
        imp += g_colsum_part[((size_t)b * NHEAD * 4 + p) * LL + t];
    v[t] = imp;
    __syncthreads();
    int cnt = 0;
    for (int k = 0; k < LL; k++) {
        float vk = v[k];
        cnt += (vk > imp) || (vk == imp && k < t);
    }
    int notp = (cnt >= KPRES) ? 1 : 0;    // rank >= K -> unpreserved
    pos[t] = notp;
    __syncthreads();
    for (int s = 1; s < LL; s <<= 1) {
        int add = (t >= s) ? pos[t - s] : 0;
        __syncthreads();
        pos[t] += add;
        __syncthreads();
    }
    if (notp) g_unp[b * RCNT + pos[t] - 1] = t;
    // --- phase 2: edge ranking (first 256 threads; i = t) ---
    if (t < HALF) {
        unsigned long long p = g_nodep_part[((size_t)b * HALF + t) * 4 + 0];
#pragma unroll
        for (int q = 1; q < 4; q++) {
            unsigned long long w = g_nodep_part[((size_t)b * HALF + t) * 4 + q];
            if (w > p) p = w;
        }
        unsigned u = (unsigned)(p >> 32);
        unsigned bits = (u & 0x80000000u) ? (u & 0x7FFFFFFFu) : ~u;
        nm[t] = __uint_as_float(bits);
        ni[t] = 255 - (int)(p & 0xFFFFFFFFu);
    }
    __syncthreads();
    if (t < HALF) {
        float vv = nm[t];
        int cnt2 = 0;
        for (int k = 0; k < HALF; k++) {
            float vk = nm[k];
            cnt2 += (vk > vv) || (vk == vv && k < t);
        }
        if (cnt2 < RCNT) {             // merged (src) edges, rank order
            g_srctok[b * RCNT + cnt2] = t;
            g_srcdst[b * RCNT + cnt2] = ni[t];
        } else {                       // unmerged even tokens, rank order
            g_unm[b * RCNT + (cnt2 - RCNT)] = 2 * t;
        }
    }
}

// ---------------- K5: fused q/k/v projection + attention --------------------
// grid: BB*NH2 blocks, 256 threads; one (batch, head) each
__global__ void k_attn(const float* __restrict__ hs,
                       const float* __restrict__ Wq, const float* __restrict__ bq,
                       const float* __restrict__ Wk, const float* __restrict__ bk,
                       const float* __restrict__ Wv, const float* __restrict__ bv) {
    int h = blockIdx.x % NH2, b = blockIdx.x / NH2;
    int t = threadIdx.x;
    __shared__ float h0[DD];
    __shared__ float wk2[DD];
    __shared__ float hbar[DD];
    __shared__ float qs[HD];
    __shared__ float red[256];
    __shared__ float att[RCNT];
    __shared__ int   toks[RCNT];
    __shared__ float qbk;
    const float* hb = hs + (size_t)b * LL * DD;
    for (int d = t; d < DD; d += 256) h0[d] = hb[d];
    if (t < RCNT) toks[t] = g_unp[b * RCNT + t];
    __syncthreads();
    // --- q head projection: 4 partial sums of 192 per output dim ---
    {
        int u = t & 63, part = t >> 6;
        float a = 0.f;
        for (int d = part * 192; d < part * 192 + 192; d++)
            a += h0[d] * Wq[(size_t)d * UDIM + h * HD + u];
        red[t] = a;
        __syncthreads();
        if (t < HD)
            qs[t] = bq[h * HD + t] + red[t] + red[t + 64] + red[t + 128] + red[t + 192];
        __syncthreads();
    }
    // --- wk2 = Wk_head @ q  (so logits = H . wk2 + q.bk) ---
    for (int d = t; d < DD; d += 256) {
        const float4* wrow = (const float4*)(Wk + (size_t)d * UDIM + h * HD);
        const float4* q4 = (const float4*)qs;
        float4 s4 = {0.f, 0.f, 0.f, 0.f};
#pragma unroll
        for (int u4 = 0; u4 < 16; u4++) {
            float4 w = wrow[u4], q = q4[u4];
            s4.x += q.x * w.x; s4.y += q.y * w.y; s4.z += q.z * w.z; s4.w += q.w * w.w;
        }
        wk2[d] = (s4.x + s4.y) + (s4.z + s4.w);
    }
    if (t == 0) {
        float a = 0.f;
        for (int u = 0; u < HD; u++) a += qs[u] * bk[h * HD + u];
        qbk = a;
    }
    __syncthreads();
    // --- logits: 2 threads per token, half a row each ---
    {
        int tok = t >> 1, half = t & 1;
        const float4* hr4 = (const float4*)(hb + (size_t)toks[tok] * DD) + half * 96;
        const float4* wk4 = (const float4*)wk2 + half * 96;
        float4 s4 = {0.f, 0.f, 0.f, 0.f};
        for (int d4 = 0; d4 < 96; d4++) {
            float4 w = wk4[d4], x = hr4[d4];
            s4.x += w.x * x.x; s4.y += w.y * x.y; s4.z += w.z * x.z; s4.w += w.w * x.w;
        }
        red[t] = (s4.x + s4.y) + (s4.z + s4.w);
    }
    __syncthreads();
    float lg = -1e30f;
    if (t < RCNT) lg = (qbk + red[2 * t] + red[2 * t + 1]) * 0.125f;   // 1/sqrt(64)
    __syncthreads();
    red[t] = lg;
    __syncthreads();
    for (int s = 128; s > 0; s >>= 1) {
        if (t < s) red[t] = fmaxf(red[t], red[t + s]);
        __syncthreads();
    }
    float mx = red[0];
    __syncthreads();
    float e = (t < RCNT) ? expf(lg - mx) : 0.f;
    red[t] = e;
    __syncthreads();
    for (int s = 128; s > 0; s >>= 1) {
        if (t < s) red[t] += red[t + s];
        __syncthreads();
    }
    float inv = 1.f / red[0];
    __syncthreads();
    if (t < RCNT) att[t] = e * inv;
    __syncthreads();
    // --- hbar = sum_t att_t * H_t (float4 over d, coalesced) ---
    if (t < DD / 4) {
        float4 a4 = {0.f, 0.f, 0.f, 0.f};
        for (int s2 = 0; s2 < RCNT; s2++) {
            float w = att[s2];
            float4 x = ((const float4*)(hb + (size_t)toks[s2] * DD))[t];
            a4.x += w * x.x; a4.y += w * x.y; a4.z += w * x.z; a4.w += w * x.w;
        }
        *(float4*)&hbar[4 * t] = a4;
    }
    __syncthreads();
    // --- ctx = hbar @ Wv_head + bv ---
    {
        int u = t & 63, part = t >> 6;
        float a = 0.f;
        for (int d = part * 192; d < part * 192 + 192; d++)
            a += hbar[d] * Wv[(size_t)d * UDIM + h * HD + u];
        red[t] = a;
        __syncthreads();
        if (t < HD)
            g_ctx[b * UDIM + h * HD + t] =
                bv[h * HD + t] + red[t] + red[t + 64] + red[t + 128] + red[t + 192];
    }
}

// ---------------- K6: assemble all 386 output rows (merge + newtok fused) ---
// grid: BB*385 + BB blocks, 192 threads
__global__ void k_rows(const float* __restrict__ hs,
                       const float* __restrict__ Wo, const float* __restrict__ bo,
                       float* __restrict__ out) {
    int blk = blockIdx.x;
    int t = threadIdx.x;
    if (blk < BB * 385) {
        int row = blk % 385, b = blk / 385;
        float4* o4 = (float4*)(out + ((size_t)b * 386 + row) * DD);
        if (row == 0) {
            const float4* s4 = (const float4*)(hs + (size_t)b * LL * DD);
            o4[t] = s4[t];
        } else if (row <= RCNT) {
            int tok = g_unm[b * RCNT + row - 1];
            const float4* s4 = (const float4*)(hs + ((size_t)b * LL + tok) * DD);
            o4[t] = s4[t];
        } else {
            int j = row - 1 - RCNT;
            __shared__ int ss[RCNT], sd[RCNT];
            if (t < RCNT) { ss[t] = g_srctok[b * RCNT + t]; sd[t] = g_srcdst[b * RCNT + t]; }
            __syncthreads();
            float4 acc = ((const float4*)(hs + ((size_t)b * LL + 2 * j + 1) * DD))[t];
            float cnt = 1.f;
            for (int s2 = 0; s2 < RCNT; s2++) {    // ascending rank == np.add.at order
                if (sd[s2] == j) {
                    float4 v = ((const float4*)(hs + ((size_t)b * LL + 2 * ss[s2]) * DD))[t];
                    acc.x += v.x; acc.y += v.y; acc.z += v.z; acc.w += v.w;
                    cnt += 1.f;
                }
            }
            float4 r; r.x = acc.x / cnt; r.y = acc.y / cnt; r.z = acc.z / cnt; r.w = acc.w / cnt;
            o4[t] = r;
        }
    } else {
        // new_token = ctx @ Wo + bo  (output row 385); 192 thr x 4 outputs
        int b = blk - BB * 385;
        __shared__ float c[UDIM];
        c[t] = g_ctx[b * UDIM + t];
        c[t + 192] = g_ctx[b * UDIM + t + 192];
        __syncthreads();
#pragma unroll
        for (int kk = 0; kk < 4; kk++) {
            int dd = t + 192 * kk;
            float acc = bo[dd];
            for (int u = 0; u < UDIM; u++)
                acc += c[u] * Wo[(size_t)u * DD + dd];
            out[((size_t)b * 386 + 385) * DD + dd] = acc;
        }
    }
}

extern "C" void kernel_launch(void* const* d_in, const int* in_sizes, int n_in,
                              void* d_out, int out_size, void* d_ws, size_t ws_size,
                              hipStream_t stream) {
    const float* hs = (const float*)d_in[0];
    const float* sc = (const float*)d_in[1];
    const float* Wq = (const float*)d_in[2];
    const float* bq = (const float*)d_in[3];
    const float* Wk = (const float*)d_in[4];
    const float* bk = (const float*)d_in[5];
    const float* Wv = (const float*)d_in[6];
    const float* bv = (const float*)d_in[7];
    const float* Wo = (const float*)d_in[8];
    const float* bo = (const float*)d_in[9];
    float* out = (float*)d_out;
    float* metric = (float*)d_ws;    // 16*512*768*4 = 25.2 MB

    k_colsum<<<BB * NHEAD * 4, 128, 0, stream>>>(sc);
    k_metric<<<BB * LL, 256, 0, stream>>>(hs, metric);
    k_sim<<<dim3(BB, 4, 4), 256, 0, stream>>>(metric);
    k_seledge<<<BB, 512, 0, stream>>>(nullptr);
    k_attn<<<BB * NH2, 256, 0, stream>>>(hs, Wq, bq, Wk, bk, Wv, bv);
    k_rows<<<BB * 385 + BB, 192, 0, stream>>>(hs, Wo, bo, out);
}

// Round 7
// 521.911 us; speedup vs baseline: 1.0845x; 1.0115x over previous
//
#include <hip/hip_runtime.h>
#include <hip/hip_bf16.h>

#define BB 16
#define LL 512
#define DD 768
#define NHEAD 12
#define HALF 256      // L/2
#define KPRES 384
#define RCNT 128      // L - K  (merged src count = unpreserved count)
#define UDIM 384
#define NH2 6
#define HD 64

// ---- small module-scope scratch (deterministic, no atomics) ----------------
__device__ float              g_colsum_part[BB * NHEAD * 4 * LL]; // 1.57 MB
__device__ float              g_norms[BB * LL];                   // 32 KB
__device__ unsigned long long g_nodep_part[BB * HALF * 4];        // 128 KB
__device__ int                g_unm[BB * RCNT];
__device__ int                g_srctok[BB * RCNT];
__device__ int                g_srcdst[BB * RCNT];
__device__ int                g_unp[BB * RCNT];
__device__ float              g_ctx[BB * UDIM];

// ---------------- K1: colsum partials (diag excluded) + row norms -----------
// grid: 768 + BB*LL blocks, 256 threads.
//   blocks [0,768): (b,h,128-row chunk) partial column sums, 2 cols/thread
//   blocks [768,768+8192): one hidden row each -> L2 norm (round-4 tree)
__global__ void k_colnorm(const float* __restrict__ sc, const float* __restrict__ hs) {
    int blk = blockIdx.x;
    int t = threadIdx.x;
    __shared__ float red[256];
    if (blk < BB * NHEAD * 4) {
        int ic = blk & 3;
        int bh = blk >> 2;                 // b*NHEAD + h
        const float* base = sc + (size_t)bh * LL * LL;
        int i0 = ic * 128;
        float ax = 0.f, ay = 0.f;
        for (int i = 0; i < 128; i++) {    // ascending i: fixed fp order per column
            float2 v = ((const float2*)(base + (size_t)(i0 + i) * LL))[t];
            ax += v.x; ay += v.y;
        }
#pragma unroll
        for (int c = 0; c < 2; c++) {
            int cj = 2 * t + c;
            if (cj >= i0 && cj < i0 + 128) {
                float d = base[(size_t)cj * LL + cj];
                if (c == 0) ax -= d; else ay -= d;
            }
        }
        g_colsum_part[(size_t)blk * LL + 2 * t] = ax;
        g_colsum_part[(size_t)blk * LL + 2 * t + 1] = ay;
    } else {
        int row = blk - BB * NHEAD * 4;    // [0, BB*LL)
        const float* src = hs + (size_t)row * DD;
        float v0 = src[t], v1 = src[t + 256], v2 = src[t + 512];
        red[t] = ((0.f + v0 * v0) + v1 * v1) + v2 * v2;   // round-4 bit pattern
        __syncthreads();
        for (int s = 128; s > 0; s >>= 1) {
            if (t < s) red[t] += red[t + s];
            __syncthreads();
        }
        if (t == 0) g_norms[row] = sqrtf(red[0]);
    }
}

// ---------------- K2: sim tile + fused row-argmax ---------------------------
// grid: (BB,4,4); 256 threads; block = 64 even-rows x 64 odd-cols
// IEEE div by norm at prefetch (bit-identical to materialized metric).
__global__ void k_sim(const float* __restrict__ hs) {
    int b = blockIdx.x, it = blockIdx.y, jt = blockIdx.z;
    int i0 = it * 64, j0 = jt * 64;
    __shared__ float As[64][20];       // rows 80 B apart: 2-way on frag reads (free)
    __shared__ float BsT[16][68];      // [k][col], pad 68: frag reads conflict-free
    __shared__ float nA[64], nB[64];
    __shared__ unsigned long long cand[64][16];
    int t  = threadIdx.x;
    int ti = t >> 4, tj = t & 15;
    if (t < 64) nA[t] = g_norms[b * LL + 2 * (i0 + t)];
    else if (t < 128) nB[t - 64] = g_norms[b * LL + 2 * (j0 + t - 64) + 1];
    float acc[4][4];
#pragma unroll
    for (int a = 0; a < 4; a++)
#pragma unroll
        for (int c = 0; c < 4; c++) acc[a][c] = 0.f;
    const float* hb = hs + (size_t)b * LL * DD;
    int sr = t >> 2, sc4 = t & 3;      // staging: thread -> (row, float4-slot)
    const float* arow = hb + (size_t)(2 * (i0 + sr)) * DD;
    const float* brow = hb + (size_t)(2 * (j0 + sr) + 1) * DD;
    __syncthreads();                   // norms visible
    float inA = nA[sr], inB = nB[sr];
    float4 a4 = ((const float4*)arow)[sc4];          // prefetch step 0
    float4 b4 = ((const float4*)brow)[sc4];
    a4.x /= inA; a4.y /= inA; a4.z /= inA; a4.w /= inA;
    b4.x /= inB; b4.y /= inB; b4.z /= inB; b4.w /= inB;
    for (int s = 0; s < 48; s++) {
        __syncthreads();
        *(float4*)&As[sr][4 * sc4] = a4;
        BsT[4 * sc4 + 0][sr] = b4.x;
        BsT[4 * sc4 + 1][sr] = b4.y;
        BsT[4 * sc4 + 2][sr] = b4.z;
        BsT[4 * sc4 + 3][sr] = b4.w;
        __syncthreads();
        if (s + 1 < 48) {                            // prefetch + divide next tile
            int d0 = (s + 1) * 16;
            a4 = ((const float4*)(arow + d0))[sc4];
            b4 = ((const float4*)(brow + d0))[sc4];
            a4.x /= inA; a4.y /= inA; a4.z /= inA; a4.w /= inA;
            b4.x /= inB; b4.y /= inB; b4.z /= inB; b4.w /= inB;
        }
#pragma unroll
        for (int c4 = 0; c4 < 4; c4++) {
            float4 av[4], bk4[4];
#pragma unroll
            for (int a = 0; a < 4; a++) av[a] = *(const float4*)&As[ti * 4 + a][4 * c4];
#pragma unroll
            for (int k = 0; k < 4; k++) bk4[k] = *(const float4*)&BsT[4 * c4 + k][4 * tj];
#pragma unroll
            for (int k = 0; k < 4; k++) {            // k ascending: same fp order
#pragma unroll
                for (int a = 0; a < 4; a++) {
                    float ak = ((const float*)&av[a])[k];
#pragma unroll
                    for (int c = 0; c < 4; c++)
                        acc[a][c] += ak * ((const float*)&bk4[k])[c];
                }
            }
        }
    }
    // pack (sim, smaller-j-wins) into sortable u64; per-thread best over 4 cols
#pragma unroll
    for (int a = 0; a < 4; a++) {
        unsigned long long bp = 0ULL;
#pragma unroll
        for (int c = 0; c < 4; c++) {
            int jg = j0 + tj * 4 + c;
            unsigned u = __float_as_uint(acc[a][c]);
            u = (u & 0x80000000u) ? ~u : (u | 0x80000000u);
            unsigned long long p = ((unsigned long long)u << 32) | (unsigned long long)(255 - jg);
            if (p > bp) bp = p;
        }
        cand[ti * 4 + a][tj] = bp;
    }
    __syncthreads();
    if (t < 64) {
        unsigned long long m = cand[t][0];
#pragma unroll
        for (int c2 = 1; c2 < 16; c2++) { unsigned long long v = cand[t][c2]; if (v > m) m = v; }
        g_nodep_part[((size_t)b * HALF + i0 + t) * 4 + jt] = m;
    }
}

// ---------------- K3: top-K select (512 thr) + edge ranking (256 thr) -------
// grid: BB blocks, 512 threads
__global__ void k_seledge(int* dummy) {
    int b = blockIdx.x, t = threadIdx.x;
    __shared__ float v[LL];
    __shared__ int pos[LL];
    __shared__ float nm[HALF];
    __shared__ int   ni[HALF];
    // --- phase 1: importance rank + compaction (thread t = token j) ---
    float imp = 0.f;
    for (int p = 0; p < NHEAD * 4; p++)
        imp += g_colsum_part[((size_t)b * NHEAD * 4 + p) * LL + t];
    v[t] = imp;
    __syncthreads();
    int cnt = 0;
    for (int k = 0; k < LL; k++) {
        float vk = v[k];
        cnt += (vk > imp) || (vk == imp && k < t);
    }
    int notp = (cnt >= KPRES) ? 1 : 0;    // rank >= K -> unpreserved
    pos[t] = notp;
    __syncthreads();
    for (int s = 1; s < LL; s <<= 1) {
        int add = (t >= s) ? pos[t - s] : 0;
        __syncthreads();
        pos[t] += add;
        __syncthreads();
    }
    if (notp) g_unp[b * RCNT + pos[t] - 1] = t;
    // --- phase 2: edge ranking (first 256 threads; i = t) ---
    if (t < HALF) {
        unsigned long long p = g_nodep_part[((size_t)b * HALF + t) * 4 + 0];
#pragma unroll
        for (int q = 1; q < 4; q++) {
            unsigned long long w = g_nodep_part[((size_t)b * HALF + t) * 4 + q];
            if (w > p) p = w;
        }
        unsigned u = (unsigned)(p >> 32);
        unsigned bits = (u & 0x80000000u) ? (u & 0x7FFFFFFFu) : ~u;
        nm[t] = __uint_as_float(bits);
        ni[t] = 255 - (int)(p & 0xFFFFFFFFu);
    }
    __syncthreads();
    if (t < HALF) {
        float vv = nm[t];
        int cnt2 = 0;
        for (int k = 0; k < HALF; k++) {
            float vk = nm[k];
            cnt2 += (vk > vv) || (vk == vv && k < t);
        }
        if (cnt2 < RCNT) {             // merged (src) edges, rank order
            g_srctok[b * RCNT + cnt2] = t;
            g_srcdst[b * RCNT + cnt2] = ni[t];
        } else {                       // unmerged even tokens, rank order
            g_unm[b * RCNT + (cnt2 - RCNT)] = 2 * t;
        }
    }
}

// ---------------- K4: fused q/k/v projection + attention --------------------
// grid: BB*NH2 blocks, 256 threads; one (batch, head) each
__global__ void k_attn(const float* __restrict__ hs,
                       const float* __restrict__ Wq, const float* __restrict__ bq,
                       const float* __restrict__ Wk, const float* __restrict__ bk,
                       const float* __restrict__ Wv, const float* __restrict__ bv) {
    int h = blockIdx.x % NH2, b = blockIdx.x / NH2;
    int t = threadIdx.x;
    __shared__ float h0[DD];
    __shared__ float wk2[DD];
    __shared__ float hbar[DD];
    __shared__ float qs[HD];
    __shared__ float red[256];
    __shared__ float att[RCNT];
    __shared__ int   toks[RCNT];
    __shared__ float qbk;
    const float* hb = hs + (size_t)b * LL * DD;
    for (int d = t; d < DD; d += 256) h0[d] = hb[d];
    if (t < RCNT) toks[t] = g_unp[b * RCNT + t];
    __syncthreads();
    // --- q head projection: 4 partial sums of 192 per output dim ---
    {
        int u = t & 63, part = t >> 6;
        float a = 0.f;
        for (int d = part * 192; d < part * 192 + 192; d++)
            a += h0[d] * Wq[(size_t)d * UDIM + h * HD + u];
        red[t] = a;
        __syncthreads();
        if (t < HD)
            qs[t] = bq[h * HD + t] + red[t] + red[t + 64] + red[t + 128] + red[t + 192];
        __syncthreads();
    }
    // --- wk2 = Wk_head @ q  (so logits = H . wk2 + q.bk) ---
    for (int d = t; d < DD; d += 256) {
        const float4* wrow = (const float4*)(Wk + (size_t)d * UDIM + h * HD);
        const float4* q4 = (const float4*)qs;
        float4 s4 = {0.f, 0.f, 0.f, 0.f};
#pragma unroll
        for (int u4 = 0; u4 < 16; u4++) {
            float4 w = wrow[u4], q = q4[u4];
            s4.x += q.x * w.x; s4.y += q.y * w.y; s4.z += q.z * w.z; s4.w += q.w * w.w;
        }
        wk2[d] = (s4.x + s4.y) + (s4.z + s4.w);
    }
    if (t == 0) {
        float a = 0.f;
        for (int u = 0; u < HD; u++) a += qs[u] * bk[h * HD + u];
        qbk = a;
    }
    __syncthreads();
    // --- logits: 2 threads per token, half a row each ---
    {
        int tok = t >> 1, half = t & 1;
        const float4* hr4 = (const float4*)(hb + (size_t)toks[tok] * DD) + half * 96;
        const float4* wk4 = (const float4*)wk2 + half * 96;
        float4 s4 = {0.f, 0.f, 0.f, 0.f};
        for (int d4 = 0; d4 < 96; d4++) {
            float4 w = wk4[d4], x = hr4[d4];
            s4.x += w.x * x.x; s4.y += w.y * x.y; s4.z += w.z * x.z; s4.w += w.w * x.w;
        }
        red[t] = (s4.x + s4.y) + (s4.z + s4.w);
    }
    __syncthreads();
    float lg = -1e30f;
    if (t < RCNT) lg = (qbk + red[2 * t] + red[2 * t + 1]) * 0.125f;   // 1/sqrt(64)
    __syncthreads();
    red[t] = lg;
    __syncthreads();
    for (int s = 128; s > 0; s >>= 1) {
        if (t < s) red[t] = fmaxf(red[t], red[t + s]);
        __syncthreads();
    }
    float mx = red[0];
    __syncthreads();
    float e = (t < RCNT) ? expf(lg - mx) : 0.f;
    red[t] = e;
    __syncthreads();
    for (int s = 128; s > 0; s >>= 1) {
        if (t < s) red[t] += red[t + s];
        __syncthreads();
    }
    float inv = 1.f / red[0];
    __syncthreads();
    if (t < RCNT) att[t] = e * inv;
    __syncthreads();
    // --- hbar = sum_t att_t * H_t (float4 over d, coalesced) ---
    if (t < DD / 4) {
        float4 a4 = {0.f, 0.f, 0.f, 0.f};
        for (int s2 = 0; s2 < RCNT; s2++) {
            float w = att[s2];
            float4 x = ((const float4*)(hb + (size_t)toks[s2] * DD))[t];
            a4.x += w * x.x; a4.y += w * x.y; a4.z += w * x.z; a4.w += w * x.w;
        }
        *(float4*)&hbar[4 * t] = a4;
    }
    __syncthreads();
    // --- ctx = hbar @ Wv_head + bv ---
    {
        int u = t & 63, part = t >> 6;
        float a = 0.f;
        for (int d = part * 192; d < part * 192 + 192; d++)
            a += hbar[d] * Wv[(size_t)d * UDIM + h * HD + u];
        red[t] = a;
        __syncthreads();
        if (t < HD)
            g_ctx[b * UDIM + h * HD + t] =
                bv[h * HD + t] + red[t] + red[t + 64] + red[t + 128] + red[t + 192];
    }
}

// ---------------- K5: assemble all 386 output rows (merge + newtok fused) ---
// grid: BB*385 + BB blocks, 192 threads
__global__ void k_rows(const float* __restrict__ hs,
                       const float* __restrict__ Wo, const float* __restrict__ bo,
                       float* __restrict__ out) {
    int blk = blockIdx.x;
    int t = threadIdx.x;
    if (blk < BB * 385) {
        int row = blk % 385, b = blk / 385;
        float4* o4 = (float4*)(out + ((size_t)b * 386 + row) * DD);
        if (row == 0) {
            const float4* s4 = (const float4*)(hs + (size_t)b * LL * DD);
            o4[t] = s4[t];
        } else if (row <= RCNT) {
            int tok = g_unm[b * RCNT + row - 1];
            const float4* s4 = (const float4*)(hs + ((size_t)b * LL + tok) * DD);
            o4[t] = s4[t];
        } else {
            int j = row - 1 - RCNT;
            __shared__ int ss[RCNT], sd[RCNT];
            if (t < RCNT) { ss[t] = g_srctok[b * RCNT + t]; sd[t] = g_srcdst[b * RCNT + t]; }
            __syncthreads();
            float4 acc = ((const float4*)(hs + ((size_t)b * LL + 2 * j + 1) * DD))[t];
            float cnt = 1.f;
            for (int s2 = 0; s2 < RCNT; s2++) {    // ascending rank == np.add.at order
                if (sd[s2] == j) {
                    float4 v = ((const float4*)(hs + ((size_t)b * LL + 2 * ss[s2]) * DD))[t];
                    acc.x += v.x; acc.y += v.y; acc.z += v.z; acc.w += v.w;
                    cnt += 1.f;
                }
            }
            float4 r; r.x = acc.x / cnt; r.y = acc.y / cnt; r.z = acc.z / cnt; r.w = acc.w / cnt;
            o4[t] = r;
        }
    } else {
        // new_token = ctx @ Wo + bo  (output row 385); 192 thr x 4 outputs
        int b = blk - BB * 385;
        __shared__ float c[UDIM];
        c[t] = g_ctx[b * UDIM + t];
        c[t + 192] = g_ctx[b * UDIM + t + 192];
        __syncthreads();
#pragma unroll
        for (int kk = 0; kk < 4; kk++) {
            int dd = t + 192 * kk;
            float acc = bo[dd];
            for (int u = 0; u < UDIM; u++)
                acc += c[u] * Wo[(size_t)u * DD + dd];
            out[((size_t)b * 386 + 385) * DD + dd] = acc;
        }
    }
}

extern "C" void kernel_launch(void* const* d_in, const int* in_sizes, int n_in,
                              void* d_out, int out_size, void* d_ws, size_t ws_size,
                              hipStream_t stream) {
    const float* hs = (const float*)d_in[0];
    const float* sc = (const float*)d_in[1];
    const float* Wq = (const float*)d_in[2];
    const float* bq = (const float*)d_in[3];
    const float* Wk = (const float*)d_in[4];
    const float* bk = (const float*)d_in[5];
    const float* Wv = (const float*)d_in[6];
    const float* bv = (const float*)d_in[7];
    const float* Wo = (const float*)d_in[8];
    const float* bo = (const float*)d_in[9];
    float* out = (float*)d_out;
    (void)d_ws; (void)ws_size;

    k_colnorm<<<BB * NHEAD * 4 + BB * LL, 256, 0, stream>>>(sc, hs);
    k_sim<<<dim3(BB, 4, 4), 256, 0, stream>>>(hs);
    k_seledge<<<BB, 512, 0, stream>>>(nullptr);
    k_attn<<<BB * NH2, 256, 0, stream>>>(hs, Wq, bq, Wk, bk, Wv, bv);
    k_rows<<<BB * 385 + BB, 192, 0, stream>>>(hs, Wo, bo, out);
}